// Round 2
// baseline (280.797 us; speedup 1.0000x reference)
//
#include <hip/hip_runtime.h>

// Gabor layer: out[i,o] = sin(x[i]·W[o] + b[o]) * exp(-0.5*||x[i]-mu[o]||^2 * gamma[o])
// B=262144 rows, O=256 outputs, D=2.  Output 256 MiB f32 -> write-bound,
// floor ~41 us at the 6.5 TB/s the harness fills demonstrate.
//
// R2: fix compile — __builtin_nontemporal_store needs a native clang ext-vector
// type, not HIP's float4 class. Algorithm unchanged from R1:
//   4 rows per thread-iteration -> wave writes 4 KiB contiguous as 4
//   back-to-back dwordx4 NT stores; x loaded as float4 pairs; sin/exp
//   prescales folded into hoisted constants; grid=2048 = one resident set.

#define NROWS 262144
#define NOUT  256
#define RPB   128                      // rows per block -> grid 2048, 8 iters
#define INV2PI 0.15915494309189535f
#define LOG2E  1.4426950408889634f

typedef float v4f __attribute__((ext_vector_type(4)));

#if __has_builtin(__builtin_amdgcn_exp2f)
#define EXP2F(v) __builtin_amdgcn_exp2f(v)
#else
#define EXP2F(v) exp2f(v)
#endif

__global__ __launch_bounds__(256, 4)
void gabor_kernel(const float* __restrict__ x,
                  const float* __restrict__ W,
                  const float* __restrict__ b,
                  const float* __restrict__ mu,
                  const float* __restrict__ gamma,
                  float* __restrict__ out)
{
    const int tid  = threadIdx.x;
    const int oq   = (tid & 63) * 4;   // this lane's 4 consecutive outputs
    const int wsub = tid >> 6;         // wave id 0..3 (uniform per wave)

    // Hoist per-output constants; fold transcendental prescales so the inner
    // loop hits v_sin_f32 / v_exp_f32 directly (saves 2 VALU/element).
    float W0[4], W1[4], bb[4], mu0[4], mu1[4], ng[4];
#pragma unroll
    for (int j = 0; j < 4; ++j) {
        const int o = oq + j;
        W0[j]  = W[o * 2 + 0] * INV2PI;          // sin(rad) = v_sin(rad/2pi)
        W1[j]  = W[o * 2 + 1] * INV2PI;
        bb[j]  = b[o] * INV2PI;
        mu0[j] = mu[o * 2 + 0];
        mu1[j] = mu[o * 2 + 1];
        ng[j]  = -0.5f * LOG2E * gamma[o];       // exp(t) = v_exp(t*log2e)
    }

    // Each wave owns rows {row0 + 16*it + rr}, rr=0..3 -> 4 KiB contiguous
    // store burst per iteration (4 x dwordx4 per lane, imm-offset addressed).
    const int row0 = blockIdx.x * RPB + wsub * 4;
    const float4* xv = reinterpret_cast<const float4*>(x);   // 2 rows / float4

#pragma unroll 2
    for (int it = 0; it < RPB / 16; ++it) {
        const int r = row0 + it * 16;
        const float4 xa = xv[(r >> 1) + 0];      // rows r, r+1 (broadcast)
        const float4 xb = xv[(r >> 1) + 1];      // rows r+2, r+3

        const float px[4] = {xa.x, xa.z, xb.x, xb.z};
        const float py[4] = {xa.y, xa.w, xb.y, xb.w};

        v4f res[4];
#pragma unroll
        for (int rr = 0; rr < 4; ++rr) {
#pragma unroll
            for (int j = 0; j < 4; ++j) {
                const float lin = __fmaf_rn(px[rr], W0[j],
                                  __fmaf_rn(py[rr], W1[j], bb[j]));
                const float dx  = px[rr] - mu0[j];
                const float dy  = py[rr] - mu1[j];
                const float d2  = __fmaf_rn(dy, dy, dx * dx);
                res[rr][j] = __builtin_amdgcn_sinf(lin) * EXP2F(d2 * ng[j]);
            }
        }

        float* orow = out + (size_t)r * NOUT + oq;
#pragma unroll
        for (int rr = 0; rr < 4; ++rr) {
            // write-once output, never re-read: NT store, don't thrash L2/L3
            __builtin_nontemporal_store(res[rr],
                reinterpret_cast<v4f*>(orow + rr * NOUT));
        }
    }
}

extern "C" void kernel_launch(void* const* d_in, const int* in_sizes, int n_in,
                              void* d_out, int out_size, void* d_ws, size_t ws_size,
                              hipStream_t stream)
{
    const float* x     = (const float*)d_in[0];  // (B, 2)
    const float* W     = (const float*)d_in[1];  // (O, 2)
    const float* b     = (const float*)d_in[2];  // (O,)
    const float* mu    = (const float*)d_in[3];  // (1, O, 2)
    const float* gamma = (const float*)d_in[4];  // (O,)
    float* out = (float*)d_out;                  // (B, O)

    const int grid = NROWS / RPB;                // 2048 blocks, 256 thr, 4 waves
    gabor_kernel<<<grid, 256, 0, stream>>>(x, W, b, mu, gamma, out);
}

// Round 3
// 269.618 us; speedup vs baseline: 1.0415x; 1.0415x over previous
//
#include <hip/hip_runtime.h>

// Gabor layer: out[i,o] = sin(x[i]·W[o] + b[o]) * exp(-0.5*||x[i]-mu[o]||^2 * gamma[o])
// B=262144 rows, O=256 outputs, D=2.  Output 256 MiB f32 -> write-bound,
// floor ~43 us at the 6.3 TB/s the harness fills demonstrate.
//
// R3 theory: R2 proved store geometry (1KiB vs 4KiB bursts, NT vs plain) is NOT
// the limiter (~110us either way, 2.5 TB/s). Remaining suspect: occupancy.
// launch_bounds(256,4) -> <=4-6 waves/SIMD; waves alternate ~480cy compute
// chains with short store windows -> store stream has gaps. This version forces
// 8 waves/SIMD (VGPR<=64): store each row immediately (res batch dropped),
// no staging arrays, plain stores. Grid 2048 x 4 waves = 8192 waves = exactly
// one fully-resident pass at 32 waves/CU.

#define NROWS 262144
#define NOUT  256
#define RPB   128                      // rows per block -> grid 2048, 8 iters
#define INV2PI 0.15915494309189535f
#define LOG2E  1.4426950408889634f

typedef float v4f __attribute__((ext_vector_type(4)));

#if __has_builtin(__builtin_amdgcn_exp2f)
#define EXP2F(v) __builtin_amdgcn_exp2f(v)
#else
#define EXP2F(v) exp2f(v)
#endif

__global__ __launch_bounds__(256, 8)   // force VGPR<=64 -> 8 waves/SIMD
void gabor_kernel(const float* __restrict__ x,
                  const float* __restrict__ W,
                  const float* __restrict__ b,
                  const float* __restrict__ mu,
                  const float* __restrict__ gamma,
                  float* __restrict__ out)
{
    const int tid  = threadIdx.x;
    const int oq   = (tid & 63) * 4;   // this lane's 4 consecutive outputs
    const int wsub = tid >> 6;         // wave id 0..3 (uniform per wave)

    // 24 constant VGPRs: per-output params with transcendental prescales folded
    // (v_sin_f32 takes revolutions, v_exp_f32 takes log2-domain).
    float W0[4], W1[4], bb[4], mu0[4], mu1[4], ng[4];
#pragma unroll
    for (int j = 0; j < 4; ++j) {
        const int o = oq + j;
        W0[j]  = W[o * 2 + 0] * INV2PI;
        W1[j]  = W[o * 2 + 1] * INV2PI;
        bb[j]  = b[o] * INV2PI;
        mu0[j] = mu[o * 2 + 0];
        mu1[j] = mu[o * 2 + 1];
        ng[j]  = -0.5f * LOG2E * gamma[o];
    }

    const int row0 = blockIdx.x * RPB + wsub * 4;
    const float4* xv = reinterpret_cast<const float4*>(x);   // 2 rows / float4

    // One row: compute 4 outputs, store immediately (keeps live VGPRs minimal).
    auto do_row = [&](float rx, float ry, float* dst) {
        v4f res;
#pragma unroll
        for (int j = 0; j < 4; ++j) {
            const float lin = __fmaf_rn(rx, W0[j], __fmaf_rn(ry, W1[j], bb[j]));
            const float dx  = rx - mu0[j];
            const float dy  = ry - mu1[j];
            const float d2  = __fmaf_rn(dy, dy, dx * dx);
            res[j] = __builtin_amdgcn_sinf(lin) * EXP2F(d2 * ng[j]);
        }
        *reinterpret_cast<v4f*>(dst) = res;   // plain store (NT reverted: lines
                                              // are dirty-in-cache from poison)
    };

#pragma unroll 2
    for (int it = 0; it < RPB / 16; ++it) {
        const int r = row0 + it * 16;
        const float4 xa = xv[(r >> 1) + 0];      // rows r, r+1 (broadcast)
        const float4 xb = xv[(r >> 1) + 1];      // rows r+2, r+3
        float* orow = out + (size_t)r * NOUT + oq;

        do_row(xa.x, xa.y, orow);
        do_row(xa.z, xa.w, orow + 1 * NOUT);
        do_row(xb.x, xb.y, orow + 2 * NOUT);
        do_row(xb.z, xb.w, orow + 3 * NOUT);
    }
}

extern "C" void kernel_launch(void* const* d_in, const int* in_sizes, int n_in,
                              void* d_out, int out_size, void* d_ws, size_t ws_size,
                              hipStream_t stream)
{
    const float* x     = (const float*)d_in[0];  // (B, 2)
    const float* W     = (const float*)d_in[1];  // (O, 2)
    const float* b     = (const float*)d_in[2];  // (O,)
    const float* mu    = (const float*)d_in[3];  // (1, O, 2)
    const float* gamma = (const float*)d_in[4];  // (O,)
    float* out = (float*)d_out;                  // (B, O)

    const int grid = NROWS / RPB;                // 2048 blocks, 256 thr, 4 waves
    gabor_kernel<<<grid, 256, 0, stream>>>(x, W, b, mu, gamma, out);
}

// Round 4
// 268.029 us; speedup vs baseline: 1.0476x; 1.0059x over previous
//
#include <hip/hip_runtime.h>

// Gabor layer: out[i,o] = sin(x[i]·W[o] + b[o]) * exp(-0.5*||x[i]-mu[o]||^2 * gamma[o])
// B=262144 rows, O=256 outputs, D=2.  Output 256 MiB f32 -> write-bound.
//
// R4 theory: R2 (store width/NT) and R3 (occupancy) were null; the harness
// fill hits 6.5 TB/s at 10% occupancy -> write path is fine, our ADDRESS
// SCHEDULE isn't. Previous versions gave each block a private window spread
// over the full 256 MiB -> ~2048 concurrent scattered write streams -> DRAM
// row thrash (~2.5 TB/s). This version grid-strides the slab like the fill:
// per iteration the whole GPU writes ONE contiguous 32-MiB slab
// (row = (it*GRID + blk)*16 + wsub*4 + rr), sweeping out[] in 8 passes.

#define NROWS 262144
#define NOUT  256
#define GRID  2048
#define RPI   16                       // rows per block per iteration
#define NIT   (NROWS / (GRID * RPI))   // 8
#define INV2PI 0.15915494309189535f
#define LOG2E  1.4426950408889634f

typedef float v4f __attribute__((ext_vector_type(4)));

#if __has_builtin(__builtin_amdgcn_exp2f)
#define EXP2F(v) __builtin_amdgcn_exp2f(v)
#else
#define EXP2F(v) exp2f(v)
#endif

__global__ __launch_bounds__(256, 8)
void gabor_kernel(const float* __restrict__ x,
                  const float* __restrict__ W,
                  const float* __restrict__ b,
                  const float* __restrict__ mu,
                  const float* __restrict__ gamma,
                  float* __restrict__ out)
{
    const int tid  = threadIdx.x;
    const int oq   = (tid & 63) * 4;   // this lane's 4 consecutive outputs
    const int wsub = tid >> 6;         // wave id 0..3 (uniform per wave)

    // Per-output constants with transcendental prescales folded
    // (v_sin_f32 takes revolutions, v_exp_f32 takes log2-domain).
    float W0[4], W1[4], bb[4], mu0[4], mu1[4], ng[4];
#pragma unroll
    for (int j = 0; j < 4; ++j) {
        const int o = oq + j;
        W0[j]  = W[o * 2 + 0] * INV2PI;
        W1[j]  = W[o * 2 + 1] * INV2PI;
        bb[j]  = b[o] * INV2PI;
        mu0[j] = mu[o * 2 + 0];
        mu1[j] = mu[o * 2 + 1];
        ng[j]  = -0.5f * LOG2E * gamma[o];
    }

    const float4* xv = reinterpret_cast<const float4*>(x);   // 2 rows / float4

    auto do_row = [&](float rx, float ry, float* dst) {
        v4f res;
#pragma unroll
        for (int j = 0; j < 4; ++j) {
            const float lin = __fmaf_rn(rx, W0[j], __fmaf_rn(ry, W1[j], bb[j]));
            const float dx  = rx - mu0[j];
            const float dy  = ry - mu1[j];
            const float d2  = __fmaf_rn(dy, dy, dx * dx);
            res[j] = __builtin_amdgcn_sinf(lin) * EXP2F(d2 * ng[j]);
        }
        *reinterpret_cast<v4f*>(dst) = res;
    };

    // Grid-stride slab sweep: at iteration `it`, ALL 2048 blocks write inside
    // the contiguous 32-MiB slab rows [it*32768, (it+1)*32768). Block b owns
    // 16 contiguous rows (16 KiB); wave wsub owns 4 of them (4 KiB).
#pragma unroll 2
    for (int it = 0; it < NIT; ++it) {
        const int r = (it * GRID + blockIdx.x) * RPI + wsub * 4;
        const float4 xa = xv[(r >> 1) + 0];      // rows r, r+1 (broadcast)
        const float4 xb = xv[(r >> 1) + 1];      // rows r+2, r+3
        float* orow = out + (size_t)r * NOUT + oq;

        do_row(xa.x, xa.y, orow);
        do_row(xa.z, xa.w, orow + 1 * NOUT);
        do_row(xb.x, xb.y, orow + 2 * NOUT);
        do_row(xb.z, xb.w, orow + 3 * NOUT);
    }
}

extern "C" void kernel_launch(void* const* d_in, const int* in_sizes, int n_in,
                              void* d_out, int out_size, void* d_ws, size_t ws_size,
                              hipStream_t stream)
{
    const float* x     = (const float*)d_in[0];  // (B, 2)
    const float* W     = (const float*)d_in[1];  // (O, 2)
    const float* b     = (const float*)d_in[2];  // (O,)
    const float* mu    = (const float*)d_in[3];  // (1, O, 2)
    const float* gamma = (const float*)d_in[4];  // (O,)
    float* out = (float*)d_out;                  // (B, O)

    gabor_kernel<<<GRID, 256, 0, stream>>>(x, W, b, mu, gamma, out);
}